// Round 1
// baseline (4046.795 us; speedup 1.0000x reference)
//
#include <hip/hip_runtime.h>

#define NPTS 4096
#define BATCH 8
#define KNN 16

// ---------------- 1x1 conv: Y[b,co,n] = bias[co] + sum_ci W[co,ci]*X[b,ci,n]
// grid: (NPTS/256, cout/COTILE, B), block 256
template<int CIN, int COTILE>
__global__ __launch_bounds__(256) void conv_kernel(
    const float* __restrict__ X, const float* __restrict__ W,
    const float* __restrict__ bias, float* __restrict__ Y, int cout) {
    int n = blockIdx.x * 256 + threadIdx.x;
    int co0 = blockIdx.y * COTILE;
    int b = blockIdx.z;
    const float* xb = X + (size_t)b * CIN * NPTS + n;
    float acc[COTILE];
#pragma unroll
    for (int j = 0; j < COTILE; ++j) acc[j] = bias[co0 + j];
    for (int ci = 0; ci < CIN; ++ci) {
        float xv = xb[(size_t)ci * NPTS];
#pragma unroll
        for (int j = 0; j < COTILE; ++j)
            acc[j] = fmaf(W[(co0 + j) * CIN + ci], xv, acc[j]);
    }
#pragma unroll
    for (int j = 0; j < COTILE; ++j)
        Y[((size_t)b * cout + co0 + j) * NPTS + n] = acc[j];
}

// ---------------- LayerNorm over point axis (per (b,c) row of 4096) + affine(g,be per-point) + ReLU, in place
// grid: (C, B), block 256
__global__ __launch_bounds__(256) void ln_relu_kernel(
    float* __restrict__ X, const float* __restrict__ g,
    const float* __restrict__ be, int C) {
    int c = blockIdx.x, b = blockIdx.y, t = threadIdx.x;
    float* row = X + ((size_t)b * C + c) * NPTS;
    double s = 0.0, s2 = 0.0;
    for (int i = t; i < NPTS; i += 256) {
        double v = (double)row[i];
        s += v; s2 += v * v;
    }
    __shared__ double sh[256], sh2[256];
    sh[t] = s; sh2[t] = s2;
    __syncthreads();
    for (int off = 128; off > 0; off >>= 1) {
        if (t < off) { sh[t] += sh[t + off]; sh2[t] += sh2[t + off]; }
        __syncthreads();
    }
    double mu = sh[0] / (double)NPTS;
    double var = sh2[0] / (double)NPTS - mu * mu;
    float rstd = (float)(1.0 / sqrt(var + 1e-5));
    float muf = (float)mu;
    for (int i = t; i < NPTS; i += 256) {
        float v = (row[i] - muf) * rstd * g[i] + be[i];
        row[i] = v > 0.f ? v : 0.f;
    }
}

// ---------------- squared norms: SQ[b,n] = sum_c X2[b,c,n]^2
__global__ __launch_bounds__(256) void sqnorm_kernel(
    const float* __restrict__ X2, float* __restrict__ SQ) {
    int n = blockIdx.x * 256 + threadIdx.x;
    int b = blockIdx.y;
    const float* xb = X2 + (size_t)b * 256 * NPTS + n;
    float s = 0.f;
    for (int c = 0; c < 256; ++c) { float v = xb[(size_t)c * NPTS]; s = fmaf(v, v, s); }
    SQ[b * NPTS + n] = s;
}

// ---------------- kNN (K=16 smallest d, ties -> smaller index, matching lax.top_k on -d)
// block = 256 threads: thread t -> query q = t&127, m-half = t>>7 (half0: m in [0,2048), half1: [2048,4096))
// grid: (NPTS/128, B)
#define TQ 128
#define TMK 32
__global__ __launch_bounds__(256) void knn_kernel(
    const float* __restrict__ X2, const float* __restrict__ SQ,
    int* __restrict__ IDX) {
    __shared__ float Mt[2][256][TMK];   // 64 KB: staged m-tile features for both halves
    int b = blockIdx.y;
    int t = threadIdx.x;
    int half = t >> 7;
    int q = t & 127;
    int n = blockIdx.x * TQ + q;
    const float* xb = X2 + (size_t)b * 256 * NPTS;
    const float* sqb = SQ + b * NPTS;
    float sqn = sqb[n];
    const float* xq = xb + n;

    float dk[KNN]; int ik[KNN];
#pragma unroll
    for (int j = 0; j < KNN; ++j) { dk[j] = 1e30f; ik[j] = -1; }

    for (int tile = 0; tile < 2048 / TMK; ++tile) {
        // cooperative stage: both halves' m-tiles (2*256*32 floats)
        for (int r = 0; r < 64; ++r) {
            int f = t + 256 * r;          // 0..16383
            int h = f >> 13;
            int rem = f & 8191;
            int c = rem >> 5;
            int j = rem & 31;
            int m = h * 2048 + tile * TMK + j;
            (&Mt[0][0][0])[f] = xb[(size_t)c * NPTS + m];
        }
        __syncthreads();

        float acc[TMK];
#pragma unroll
        for (int j = 0; j < TMK; ++j) acc[j] = 0.f;
        for (int c = 0; c < 256; ++c) {
            float fq = xq[(size_t)c * NPTS];
            const float* mrow = &Mt[half][c][0];
#pragma unroll
            for (int j = 0; j < TMK; ++j) acc[j] = fmaf(fq, mrow[j], acc[j]);
        }
        int mbase = half * 2048 + tile * TMK;
#pragma unroll
        for (int j = 0; j < TMK; ++j) {
            float d = sqn + sqb[mbase + j] - 2.f * acc[j];
            if (d < dk[KNN - 1]) {              // strict less: ascending-m scan keeps smaller index on ties
                dk[KNN - 1] = d; ik[KNN - 1] = mbase + j;
#pragma unroll
                for (int s = KNN - 1; s > 0; --s) {
                    if (dk[s] < dk[s - 1]) {
                        float td = dk[s]; dk[s] = dk[s - 1]; dk[s - 1] = td;
                        int ti = ik[s]; ik[s] = ik[s - 1]; ik[s - 1] = ti;
                    }
                }
            }
        }
        __syncthreads();
    }

    // merge the two sorted halves per query (half0 indices < half1 indices, so <= prefers lower index)
    float* dls = &Mt[0][0][0];            // 128*32 floats
    int* ils = (int*)(dls + TQ * 32);     // 128*32 ints
    int base = q * 32 + half * KNN;
#pragma unroll
    for (int j = 0; j < KNN; ++j) { dls[base + j] = dk[j]; ils[base + j] = ik[j]; }
    __syncthreads();
    if (half == 0) {
        const float* da = dls + q * 32;
        const int* iarr = ils + q * 32;
        int ia = 0, ib = 0;
        int* outp = IDX + ((size_t)b * NPTS + n) * KNN;
        for (int k = 0; k < KNN; ++k) {
            bool ta = (ia < KNN) && ((ib >= KNN) || (da[ia] <= da[KNN + ib]));
            outp[k] = ta ? iarr[ia] : iarr[KNN + ib];
            if (ta) ++ia; else ++ib;
        }
    }
}

// ---------------- gather neighbors + max over K: E[b,c,n] = max_k X2[b,c,idx[b,n,k]]
__global__ __launch_bounds__(256) void gather_max_kernel(
    const float* __restrict__ X2, const int* __restrict__ IDX,
    float* __restrict__ E) {
    int n = blockIdx.x * 256 + threadIdx.x;
    int b = blockIdx.y;
    int id[KNN];
#pragma unroll
    for (int k = 0; k < KNN; ++k) id[k] = IDX[((size_t)b * NPTS + n) * KNN + k];
    const float* xb = X2 + (size_t)b * 256 * NPTS;
    float* eb = E + (size_t)b * 256 * NPTS + n;
    for (int c = 0; c < 256; ++c) {
        const float* row = xb + (size_t)c * NPTS;
        float m = row[id[0]];
#pragma unroll
        for (int k = 1; k < KNN; ++k) m = fmaxf(m, row[id[k]]);
        eb[(size_t)c * NPTS] = m;
    }
}

// ---------------- mean over points: P[b,c] = mean_n E[b,c,n]
__global__ __launch_bounds__(256) void pool_kernel(
    const float* __restrict__ E, float* __restrict__ P) {
    int c = blockIdx.x, b = blockIdx.y, t = threadIdx.x;
    const float* row = E + ((size_t)b * 256 + c) * NPTS;
    double s = 0.0;
    for (int i = t; i < NPTS; i += 256) s += (double)row[i];
    __shared__ double sh[256];
    sh[t] = s; __syncthreads();
    for (int off = 128; off > 0; off >>= 1) {
        if (t < off) sh[t] += sh[t + off];
        __syncthreads();
    }
    if (t == 0) P[b * 256 + c] = (float)(sh[0] / (double)NPTS);
}

// ---------------- tiny MLP: 256 -> 128 relu -> 64 relu -> 1, all 8 batches in one block
__global__ __launch_bounds__(256) void mlp_kernel(
    const float* __restrict__ P,
    const float* __restrict__ gw0, const float* __restrict__ gb0,
    const float* __restrict__ gw1, const float* __restrict__ gb1,
    const float* __restrict__ gw2, const float* __restrict__ gb2,
    float* __restrict__ out) {
    __shared__ float h1[BATCH][128];
    __shared__ float h2[BATCH][64];
    int t = threadIdx.x;
    for (int o = t; o < BATCH * 128; o += 256) {
        int b = o >> 7, j = o & 127;
        const float* p = P + b * 256;
        const float* w = gw0 + j * 256;
        double acc = 0.0;
        for (int c = 0; c < 256; ++c) acc += (double)p[c] * (double)w[c];
        float v = gb0[j] + (float)acc;
        h1[b][j] = v > 0.f ? v : 0.f;
    }
    __syncthreads();
    for (int o = t; o < BATCH * 64; o += 256) {
        int b = o >> 6, j = o & 63;
        const float* w = gw1 + j * 128;
        double acc = 0.0;
        for (int c = 0; c < 128; ++c) acc += (double)h1[b][c] * (double)w[c];
        float v = gb1[j] + (float)acc;
        h2[b][j] = v > 0.f ? v : 0.f;
    }
    __syncthreads();
    if (t < BATCH) {
        double acc = 0.0;
        for (int c = 0; c < 64; ++c) acc += (double)h2[t][c] * (double)gw2[c];
        out[t] = gb2[0] + (float)acc;
    }
}

extern "C" void kernel_launch(void* const* d_in, const int* in_sizes, int n_in,
                              void* d_out, int out_size, void* d_ws, size_t ws_size,
                              hipStream_t stream) {
    const float* pc  = (const float*)d_in[0];   // [8,3,4096]
    const float* w0  = (const float*)d_in[1];   // [64,3]
    const float* b0  = (const float*)d_in[2];
    const float* g0  = (const float*)d_in[3];
    const float* be0 = (const float*)d_in[4];
    const float* w1  = (const float*)d_in[5];   // [128,64]
    const float* b1  = (const float*)d_in[6];
    const float* g1  = (const float*)d_in[7];
    const float* be1 = (const float*)d_in[8];
    const float* w2  = (const float*)d_in[9];   // [256,128]
    const float* b2  = (const float*)d_in[10];
    const float* g2  = (const float*)d_in[11];
    const float* be2 = (const float*)d_in[12];
    const float* gw0 = (const float*)d_in[13];  // [128,256]
    const float* gb0 = (const float*)d_in[14];
    const float* gw1 = (const float*)d_in[15];  // [64,128]
    const float* gb1 = (const float*)d_in[16];
    const float* gw2 = (const float*)d_in[17];  // [1,64]
    const float* gb2 = (const float*)d_in[18];
    float* out = (float*)d_out;

    float* ws = (float*)d_ws;
    float* X0 = ws;                                   // 8*64*4096   = 2,097,152
    float* X1 = X0 + (size_t)BATCH * 64 * NPTS;       // 8*128*4096  = 4,194,304
    float* X2 = X1 + (size_t)BATCH * 128 * NPTS;      // 8*256*4096  = 8,388,608
    float* E  = X2 + (size_t)BATCH * 256 * NPTS;      // 8*256*4096  = 8,388,608
    float* SQ = E  + (size_t)BATCH * 256 * NPTS;      // 8*4096
    float* P  = SQ + (size_t)BATCH * NPTS;            // 8*256
    int*  IDX = (int*)(P + BATCH * 256);              // 8*4096*16 ints

    // conv0: 3 -> 64
    conv_kernel<3, 4><<<dim3(NPTS / 256, 64 / 4, BATCH), 256, 0, stream>>>(pc, w0, b0, X0, 64);
    ln_relu_kernel<<<dim3(64, BATCH), 256, 0, stream>>>(X0, g0, be0, 64);
    // conv1: 64 -> 128
    conv_kernel<64, 4><<<dim3(NPTS / 256, 128 / 4, BATCH), 256, 0, stream>>>(X0, w1, b1, X1, 128);
    ln_relu_kernel<<<dim3(128, BATCH), 256, 0, stream>>>(X1, g1, be1, 128);
    // conv2: 128 -> 256
    conv_kernel<128, 4><<<dim3(NPTS / 256, 256 / 4, BATCH), 256, 0, stream>>>(X1, w2, b2, X2, 256);
    ln_relu_kernel<<<dim3(256, BATCH), 256, 0, stream>>>(X2, g2, be2, 256);
    // edge conv
    sqnorm_kernel<<<dim3(NPTS / 256, BATCH), 256, 0, stream>>>(X2, SQ);
    knn_kernel<<<dim3(NPTS / TQ, BATCH), 256, 0, stream>>>(X2, SQ, IDX);
    gather_max_kernel<<<dim3(NPTS / 256, BATCH), 256, 0, stream>>>(X2, IDX, E);
    // pool + MLP
    pool_kernel<<<dim3(256, BATCH), 256, 0, stream>>>(E, P);
    mlp_kernel<<<1, 256, 0, stream>>>(P, gw0, gb0, gw1, gb1, gw2, gb2, out);
}

// Round 2
// 1384.219 us; speedup vs baseline: 2.9235x; 2.9235x over previous
//
#include <hip/hip_runtime.h>
#include <stdint.h>

#define NPTS 4096
#define BATCH 8
#define KNN 16

typedef __attribute__((ext_vector_type(8))) short short8;
typedef __attribute__((ext_vector_type(4))) float f32x4;

// ---------------- 1x1 conv: Y[b,co,n] = bias[co] + sum_ci W[co,ci]*X[b,ci,n]
template<int CIN, int COTILE>
__global__ __launch_bounds__(256) void conv_kernel(
    const float* __restrict__ X, const float* __restrict__ W,
    const float* __restrict__ bias, float* __restrict__ Y, int cout) {
    int n = blockIdx.x * 256 + threadIdx.x;
    int co0 = blockIdx.y * COTILE;
    int b = blockIdx.z;
    const float* xb = X + (size_t)b * CIN * NPTS + n;
    float acc[COTILE];
#pragma unroll
    for (int j = 0; j < COTILE; ++j) acc[j] = bias[co0 + j];
    for (int ci = 0; ci < CIN; ++ci) {
        float xv = xb[(size_t)ci * NPTS];
#pragma unroll
        for (int j = 0; j < COTILE; ++j)
            acc[j] = fmaf(W[(co0 + j) * CIN + ci], xv, acc[j]);
    }
#pragma unroll
    for (int j = 0; j < COTILE; ++j)
        Y[((size_t)b * cout + co0 + j) * NPTS + n] = acc[j];
}

// ---------------- LayerNorm over point axis + affine + ReLU, in place
__global__ __launch_bounds__(256) void ln_relu_kernel(
    float* __restrict__ X, const float* __restrict__ g,
    const float* __restrict__ be, int C) {
    int c = blockIdx.x, b = blockIdx.y, t = threadIdx.x;
    float* row = X + ((size_t)b * C + c) * NPTS;
    double s = 0.0, s2 = 0.0;
    for (int i = t; i < NPTS; i += 256) {
        double v = (double)row[i];
        s += v; s2 += v * v;
    }
    __shared__ double sh[256], sh2[256];
    sh[t] = s; sh2[t] = s2;
    __syncthreads();
    for (int off = 128; off > 0; off >>= 1) {
        if (t < off) { sh[t] += sh[t + off]; sh2[t] += sh2[t + off]; }
        __syncthreads();
    }
    double mu = sh[0] / (double)NPTS;
    double var = sh2[0] / (double)NPTS - mu * mu;
    float rstd = (float)(1.0 / sqrt(var + 1e-5));
    float muf = (float)mu;
    for (int i = t; i < NPTS; i += 256) {
        float v = (row[i] - muf) * rstd * g[i] + be[i];
        row[i] = v > 0.f ? v : 0.f;
    }
}

// ---------------- squared norms: SQ[b,n] = sum_c X2[b,c,n]^2  (fp32, matches ref path)
__global__ __launch_bounds__(256) void sqnorm_kernel(
    const float* __restrict__ X2, float* __restrict__ SQ) {
    int n = blockIdx.x * 256 + threadIdx.x;
    int b = blockIdx.y;
    const float* xb = X2 + (size_t)b * 256 * NPTS + n;
    float s = 0.f;
    for (int c = 0; c < 256; ++c) { float v = xb[(size_t)c * NPTS]; s = fmaf(v, v, s); }
    SQ[b * NPTS + n] = s;
}

// ---------------- bf16 hi/lo split conversion -------------------------------
// X2: [B][256][NPTS] fp32  ->  Fc: [B][8][NPTS][88] bf16
// chunk cc (0..3) holds hi of c = cc*64..cc*64+63; chunk 4+cc holds lo.
// Row padded 64->88 bf16 (176 B = 16B-aligned, 44-dword LDS stride -> 2-way banks).
#define ROW_E 88
#define ROW_B 176

__device__ inline unsigned short f2bf_rne(float x) {
    union { float f; unsigned u; } v; v.f = x;
    unsigned u = v.u;
    return (unsigned short)((u + 0x7FFFu + ((u >> 16) & 1u)) >> 16);
}
__device__ inline float bf2f(unsigned short h) {
    union { float f; unsigned u; } v; v.u = ((unsigned)h) << 16;
    return v.f;
}

__global__ __launch_bounds__(256) void convert_kernel(
    const float* __restrict__ X2, unsigned short* __restrict__ Fc) {
    __shared__ float T[64][65];
    int b = blockIdx.y;
    int n0 = blockIdx.x * 64;
    int t = threadIdx.x;
    for (int cc = 0; cc < 4; ++cc) {
        for (int r = 0; r < 16; ++r) {
            int cl = r * 4 + (t >> 6);
            T[cl][t & 63] = X2[((size_t)b * 256 + cc * 64 + cl) * NPTS + n0 + (t & 63)];
        }
        __syncthreads();
        int n_loc = t >> 2, cq = t & 3;
        size_t base_hi = (((size_t)(b * 8 + cc) * NPTS) + n0 + n_loc) * ROW_E;
        size_t base_lo = (((size_t)(b * 8 + 4 + cc) * NPTS) + n0 + n_loc) * ROW_E;
#pragma unroll
        for (int j = 0; j < 16; ++j) {
            int c = cq * 16 + j;
            float x = T[c][n_loc];
            unsigned short h = f2bf_rne(x);
            float lo = x - bf2f(h);
            Fc[base_hi + c] = h;
            Fc[base_lo + c] = f2bf_rne(lo);
        }
        __syncthreads();
    }
}

// ---------------- fused MFMA kNN --------------------------------------------
// grid (32 query-tiles, B), 256 threads (4 waves in 2x2 of 64q x 64k).
// G = Fcat . Fcat^T via 16x16x32 bf16 MFMA, K=512 (hi|lo). d' = sq[m] - 2*G
// (per-query constant sq[n] dropped: ordering invariant).
#define A_BYTES (128 * ROW_B)      // 22528
#define STAGE_BYTES (2 * A_BYTES)  // 45056

__device__ inline void async_cp16(const void* g, void* l) {
    __builtin_amdgcn_global_load_lds((const __attribute__((address_space(1))) void*)g,
                                     (__attribute__((address_space(3))) void*)l, 16, 0, 0);
}

__global__ __launch_bounds__(256) void knn_mfma_kernel(
    const unsigned short* __restrict__ Fc, const float* __restrict__ SQ,
    int* __restrict__ IDX) {
    __shared__ __align__(16) char smem[STAGE_BYTES];   // union: stage A|B, Gbuf, merge
    int b = blockIdx.y;
    int q0 = blockIdx.x * 128;
    int t = threadIdx.x;
    int lane = t & 63;
    int wv = t >> 6;
    int wq = wv & 1, wk = wv >> 1;
    int quad = lane >> 4;
    int l15 = lane & 15;
    const float* sqb = SQ + b * NPTS;
    const char* FcB = (const char*)Fc + (size_t)b * 8 * NPTS * ROW_B;

    float dk[KNN]; int ik[KNN];
#pragma unroll
    for (int j = 0; j < KNN; ++j) { dk[j] = 1e30f; ik[j] = 0x7fffffff; }

    for (int kt = 0; kt < 32; ++kt) {
        int k0 = kt * 128;
        f32x4 acc[4][4];
#pragma unroll
        for (int i = 0; i < 4; ++i)
#pragma unroll
            for (int j = 0; j < 4; ++j) acc[i][j] = (f32x4){0.f, 0.f, 0.f, 0.f};

        for (int kc = 0; kc < 8; ++kc) {
            __syncthreads();   // previous readers of smem done
            const char* gA = FcB + ((size_t)kc * NPTS + q0) * ROW_B;
            const char* gB = FcB + ((size_t)kc * NPTS + k0) * ROW_B;
#pragma unroll
            for (int i = 0; i < 11; ++i) {
                int F = (i * 4 + wv) * 1024 + lane * 16;
                const char* g = (F < A_BYTES) ? (gA + F) : (gB + (F - A_BYTES));
                async_cp16(g, smem + F);
            }
            __syncthreads();   // staging drained (vmcnt(0) before barrier)
#pragma unroll
            for (int ks = 0; ks < 2; ++ks) {
                int coff = ks * 64 + quad * 16;   // bytes into the 64-bf16 payload
                short8 a[4], bf[4];
#pragma unroll
                for (int tq = 0; tq < 4; ++tq)
                    a[tq] = *(const short8*)(smem + (wq * 64 + tq * 16 + l15) * ROW_B + coff);
#pragma unroll
                for (int tk = 0; tk < 4; ++tk)
                    bf[tk] = *(const short8*)(smem + A_BYTES + (wk * 64 + tk * 16 + l15) * ROW_B + coff);
#pragma unroll
                for (int tq = 0; tq < 4; ++tq)
#pragma unroll
                    for (int tk = 0; tk < 4; ++tk)
                        acc[tq][tk] = __builtin_amdgcn_mfma_f32_16x16x32_bf16(
                            a[tq], bf[tk], acc[tq][tk], 0, 0, 0);
            }
        }

        // selection: two 64-key halves through LDS [key][query(+pad)] stride 132
        float* Gbuf = (float*)smem;
#pragma unroll 1
        for (int h = 0; h < 2; ++h) {
            __syncthreads();   // MFMA frag reads / previous select done
            if (wk == h) {
#pragma unroll
                for (int tk = 0; tk < 4; ++tk) {
                    int klocal = tk * 16 + l15;
#pragma unroll
                    for (int tq = 0; tq < 4; ++tq)
                        *(f32x4*)(Gbuf + klocal * 132 + wq * 64 + tq * 16 + quad * 4) = acc[tq][tk];
                }
            }
            __syncthreads();
            int q = t & 127, sub = t >> 7;
#pragma unroll 1
            for (int j = 0; j < 32; ++j) {
                int klocal = sub * 32 + j;
                float gv = Gbuf[klocal * 132 + q];
                int kg = k0 + h * 64 + klocal;
                float d = sqb[kg] - 2.0f * gv;
                if (d < dk[KNN - 1]) {   // strict less: ascending index scan keeps smaller idx on ties
                    dk[KNN - 1] = d; ik[KNN - 1] = kg;
#pragma unroll
                    for (int s = KNN - 1; s > 0; --s) {
                        if (dk[s] < dk[s - 1]) {
                            float td = dk[s]; dk[s] = dk[s - 1]; dk[s - 1] = td;
                            int ti = ik[s]; ik[s] = ik[s - 1]; ik[s - 1] = ti;
                        }
                    }
                }
            }
        }
    }

    // final merge of the two per-query partial lists (threads t and t+128)
    __syncthreads();
    float* dls = (float*)smem;                 // [256][17] padded
    int* ils = (int*)(smem + 256 * 17 * 4);    // [256][17]
#pragma unroll
    for (int j = 0; j < KNN; ++j) { dls[t * 17 + j] = dk[j]; ils[t * 17 + j] = ik[j]; }
    __syncthreads();
    if (t < 128) {
        const float* da = dls + t * 17;
        const float* db = dls + (t + 128) * 17;
        const int* ia_ = ils + t * 17;
        const int* ib_ = ils + (t + 128) * 17;
        int ia = 0, ibx = 0;
        int* outp = IDX + ((size_t)b * NPTS + q0 + t) * KNN;
        for (int k = 0; k < KNN; ++k) {
            bool ta;
            if (ia >= KNN) ta = false;
            else if (ibx >= KNN) ta = true;
            else {
                float x = da[ia], y = db[ibx];
                ta = (x < y) || (x == y && ia_[ia] < ib_[ibx]);
            }
            outp[k] = ta ? ia_[ia++] : ib_[ibx++];
        }
    }
}

// ---------------- gather neighbors + max over K
__global__ __launch_bounds__(256) void gather_max_kernel(
    const float* __restrict__ X2, const int* __restrict__ IDX,
    float* __restrict__ E) {
    int n = blockIdx.x * 256 + threadIdx.x;
    int b = blockIdx.y;
    int id[KNN];
#pragma unroll
    for (int k = 0; k < KNN; ++k) id[k] = IDX[((size_t)b * NPTS + n) * KNN + k];
    const float* xb = X2 + (size_t)b * 256 * NPTS;
    float* eb = E + (size_t)b * 256 * NPTS + n;
    for (int c = 0; c < 256; ++c) {
        const float* row = xb + (size_t)c * NPTS;
        float m = row[id[0]];
#pragma unroll
        for (int k = 1; k < KNN; ++k) m = fmaxf(m, row[id[k]]);
        eb[(size_t)c * NPTS] = m;
    }
}

// ---------------- mean over points
__global__ __launch_bounds__(256) void pool_kernel(
    const float* __restrict__ E, float* __restrict__ P) {
    int c = blockIdx.x, b = blockIdx.y, t = threadIdx.x;
    const float* row = E + ((size_t)b * 256 + c) * NPTS;
    double s = 0.0;
    for (int i = t; i < NPTS; i += 256) s += (double)row[i];
    __shared__ double sh[256];
    sh[t] = s; __syncthreads();
    for (int off = 128; off > 0; off >>= 1) {
        if (t < off) sh[t] += sh[t + off];
        __syncthreads();
    }
    if (t == 0) P[b * 256 + c] = (float)(sh[0] / (double)NPTS);
}

// ---------------- tiny MLP: 256 -> 128 relu -> 64 relu -> 1
__global__ __launch_bounds__(256) void mlp_kernel(
    const float* __restrict__ P,
    const float* __restrict__ gw0, const float* __restrict__ gb0,
    const float* __restrict__ gw1, const float* __restrict__ gb1,
    const float* __restrict__ gw2, const float* __restrict__ gb2,
    float* __restrict__ out) {
    __shared__ float h1[BATCH][128];
    __shared__ float h2[BATCH][64];
    int t = threadIdx.x;
    for (int o = t; o < BATCH * 128; o += 256) {
        int b = o >> 7, j = o & 127;
        const float* p = P + b * 256;
        const float* w = gw0 + j * 256;
        double acc = 0.0;
        for (int c = 0; c < 256; ++c) acc += (double)p[c] * (double)w[c];
        float v = gb0[j] + (float)acc;
        h1[b][j] = v > 0.f ? v : 0.f;
    }
    __syncthreads();
    for (int o = t; o < BATCH * 64; o += 256) {
        int b = o >> 6, j = o & 63;
        const float* w = gw1 + j * 128;
        double acc = 0.0;
        for (int c = 0; c < 128; ++c) acc += (double)h1[b][c] * (double)w[c];
        float v = gb1[j] + (float)acc;
        h2[b][j] = v > 0.f ? v : 0.f;
    }
    __syncthreads();
    if (t < BATCH) {
        double acc = 0.0;
        for (int c = 0; c < 64; ++c) acc += (double)h2[t][c] * (double)gw2[c];
        out[t] = gb2[0] + (float)acc;
    }
}

extern "C" void kernel_launch(void* const* d_in, const int* in_sizes, int n_in,
                              void* d_out, int out_size, void* d_ws, size_t ws_size,
                              hipStream_t stream) {
    const float* pc  = (const float*)d_in[0];
    const float* w0  = (const float*)d_in[1];
    const float* b0  = (const float*)d_in[2];
    const float* g0  = (const float*)d_in[3];
    const float* be0 = (const float*)d_in[4];
    const float* w1  = (const float*)d_in[5];
    const float* b1  = (const float*)d_in[6];
    const float* g1  = (const float*)d_in[7];
    const float* be1 = (const float*)d_in[8];
    const float* w2  = (const float*)d_in[9];
    const float* b2  = (const float*)d_in[10];
    const float* g2  = (const float*)d_in[11];
    const float* be2 = (const float*)d_in[12];
    const float* gw0 = (const float*)d_in[13];
    const float* gb0 = (const float*)d_in[14];
    const float* gw1 = (const float*)d_in[15];
    const float* gb1 = (const float*)d_in[16];
    const float* gw2 = (const float*)d_in[17];
    const float* gb2 = (const float*)d_in[18];
    float* out = (float*)d_out;

    // ws layout (region R is time-multiplexed: X1 -> Fc -> E)
    float* ws = (float*)d_ws;
    float* X0 = ws;                                   // 2,097,152 f
    float* X2 = X0 + 2097152;                         // 8,388,608 f
    float* R  = X2 + 8388608;                         // 11,534,336 f (46.1 MB)
    float* X1 = R;
    unsigned short* Fc = (unsigned short*)R;
    float* E  = R;
    float* SQ = R + 11534336;                         // 32,768 f
    float* P  = SQ + 32768;                           // 2,048 f
    int*  IDX = (int*)(P + 2048);                     // 524,288 i

    conv_kernel<3, 4><<<dim3(NPTS / 256, 64 / 4, BATCH), 256, 0, stream>>>(pc, w0, b0, X0, 64);
    ln_relu_kernel<<<dim3(64, BATCH), 256, 0, stream>>>(X0, g0, be0, 64);
    conv_kernel<64, 4><<<dim3(NPTS / 256, 128 / 4, BATCH), 256, 0, stream>>>(X0, w1, b1, X1, 128);
    ln_relu_kernel<<<dim3(128, BATCH), 256, 0, stream>>>(X1, g1, be1, 128);
    conv_kernel<128, 4><<<dim3(NPTS / 256, 256 / 4, BATCH), 256, 0, stream>>>(X1, w2, b2, X2, 256);
    ln_relu_kernel<<<dim3(256, BATCH), 256, 0, stream>>>(X2, g2, be2, 256);

    sqnorm_kernel<<<dim3(NPTS / 256, BATCH), 256, 0, stream>>>(X2, SQ);
    convert_kernel<<<dim3(NPTS / 64, BATCH), 256, 0, stream>>>(X2, Fc);   // overwrites X1 (dead)
    knn_mfma_kernel<<<dim3(32, BATCH), 256, 0, stream>>>(Fc, SQ, IDX);
    gather_max_kernel<<<dim3(NPTS / 256, BATCH), 256, 0, stream>>>(X2, IDX, E);  // overwrites Fc (dead)

    pool_kernel<<<dim3(256, BATCH), 256, 0, stream>>>(E, P);
    mlp_kernel<<<1, 256, 0, stream>>>(P, gw0, gb0, gw1, gb1, gw2, gb2, out);
}